// Round 7
// baseline (227.104 us; speedup 1.0000x reference)
//
#include <hip/hip_runtime.h>
#include <cstdint>

#define BATCH 2
#define SEQ   2048
#define EMB   1024
#define NHEAD 16
#define HDIM  64
#define NTOK  (BATCH*SEQ)

typedef __attribute__((ext_vector_type(8))) short bf16x8;
typedef __attribute__((ext_vector_type(8))) short short8;
typedef __attribute__((ext_vector_type(4))) float f32x4;

__device__ inline unsigned short f2bf(float f) {
    unsigned u = __float_as_uint(f);
    u += 0x7FFF + ((u >> 16) & 1);          // RNE
    return (unsigned short)(u >> 16);
}

__device__ inline unsigned cvt_pk_bf16(float lo, float hi) {
    unsigned r;
    asm("v_cvt_pk_bf16_f32 %0, %1, %2" : "=v"(r) : "v"(lo), "v"(hi));
    return r;
}

__device__ inline void gload16(const void* g, void* lds) {
    __builtin_amdgcn_global_load_lds(
        (const __attribute__((address_space(1))) unsigned int*)g,
        (__attribute__((address_space(3))) unsigned int*)lds, 16, 0, 0);
}

// ---------------------------------------------------------------------------
// x fp32 -> bf16
__global__ __launch_bounds__(256)
void conv_x(const float* __restrict__ x, unsigned short* __restrict__ xb) {
    int i = (blockIdx.x * 256 + threadIdx.x) * 8;
    float4 a = *(const float4*)(x + i);
    float4 b = *(const float4*)(x + i + 4);
    short8 o;
    o[0]=f2bf(a.x); o[1]=f2bf(a.y); o[2]=f2bf(a.z); o[3]=f2bf(a.w);
    o[4]=f2bf(b.x); o[5]=f2bf(b.y); o[6]=f2bf(b.z); o[7]=f2bf(b.w);
    *(short8*)(xb + i) = o;
}

// W[k][n] fp32 -> Wt[n][k] bf16 (4 matrices, z-indexed), 64x64 tiles via LDS
__global__ __launch_bounds__(256)
void conv_wt(const float* __restrict__ Wq, const float* __restrict__ Wk,
             const float* __restrict__ Wv, const float* __restrict__ Wo,
             unsigned short* __restrict__ Wt) {
    const float* W = blockIdx.z==0?Wq : blockIdx.z==1?Wk : blockIdx.z==2?Wv : Wo;
    unsigned short* out = Wt + (size_t)blockIdx.z * EMB * EMB;
    __shared__ float T[64][68];
    const int t = threadIdx.x;
    const int k0 = blockIdx.x * 64, n0 = blockIdx.y * 64;
    #pragma unroll
    for (int rr = 0; rr < 4; ++rr) {
        int row = (t >> 4) + 16 * rr;
        float4 v = *(const float4*)(W + (size_t)(k0+row)*EMB + n0 + (t&15)*4);
        *(float4*)&T[row][(t&15)*4] = v;
    }
    __syncthreads();
    #pragma unroll
    for (int it = 0; it < 2; ++it) {
        int ci = it*256 + t;
        int nr = ci >> 3, kc = ci & 7;
        short8 o;
        #pragma unroll
        for (int j = 0; j < 8; ++j) o[j] = f2bf(T[kc*8+j][nr]);
        *(short8*)(out + (size_t)(n0+nr)*EMB + k0 + kc*8) = o;
    }
}

// V [B,S,H*D] bf16 -> Vt [B*H, D, S] bf16. 64x64 tiles, LDS stride 65.
__global__ __launch_bounds__(256)
void transpose_v(const unsigned short* __restrict__ Vb, unsigned short* __restrict__ Vt) {
    __shared__ unsigned short T[64*65];
    const int t = threadIdx.x;
    const int s0 = blockIdx.x * 64;
    const int bh = blockIdx.y;
    const int b = bh >> 4, h = bh & 15;
    const unsigned short* src = Vb + ((size_t)b*SEQ + s0)*EMB + h*HDIM;
    #pragma unroll
    for (int it = 0; it < 2; ++it) {
        int ci = it*256 + t;
        int r = ci >> 3, c = ci & 7;            // r = s-row, c = d-chunk
        short8 v = *(const short8*)(src + (size_t)r*EMB + c*8);
        #pragma unroll
        for (int j = 0; j < 8; ++j) T[r*65 + c*8 + j] = (unsigned short)v[j];
    }
    __syncthreads();
    unsigned short* dst = Vt + (size_t)bh * HDIM * SEQ + s0;
    #pragma unroll
    for (int it = 0; it < 2; ++it) {
        int ci = it*256 + t;
        int d = ci >> 3, c = ci & 7;            // d = out row, c = s-chunk
        short8 o;
        #pragma unroll
        for (int j = 0; j < 8; ++j) o[j] = (short)T[(c*8 + j)*65 + d];
        *(short8*)(dst + (size_t)d*SEQ + c*8) = o;
    }
}

// ---------------------------------------------------------------------------
// bf16 MFMA GEMM, 128x128 tile, BK=32, 4 waves, double-buffered staging.
// Q output is scaled by 0.125*log2(e) so attn scores are in log2 units.
__global__ __launch_bounds__(256)
void gemm_qkv(const unsigned short* __restrict__ xb, const unsigned short* __restrict__ Wt,
              const float* __restrict__ bq, const float* __restrict__ bk,
              const float* __restrict__ bv,
              unsigned short* __restrict__ Qb, unsigned short* __restrict__ Kb,
              unsigned short* __restrict__ Vb) {
    const int z = blockIdx.z;
    const unsigned short* W = Wt + (size_t)z * EMB * EMB;
    const float* bias = z==0 ? bq : z==1 ? bk : bv;
    unsigned short* out = z==0 ? Qb : z==1 ? Kb : Vb;
    const float scale = z==0 ? (0.125f * 1.44269504f) : 1.0f;

    __shared__ __align__(16) unsigned short As[2][128*32];
    __shared__ __align__(16) unsigned short Bs[2][128*32];

    const int tid = threadIdx.x, lane = tid & 63, wid = tid >> 6;
    const int m0 = blockIdx.y * 128, n0 = blockIdx.x * 128;
    const int wr = wid >> 1, wc = wid & 1;

    const int ci0 = tid, ci1 = 256 + tid;
    const int row0 = ci0 >> 2, c0 = (ci0 & 3) ^ ((row0 >> 1) & 3);
    const int row1 = ci1 >> 2, c1 = (ci1 & 3) ^ ((row1 >> 1) & 3);
    const int dst0 = wid*64, dst1 = 256 + wid*64;

    f32x4 acc[4][4];
    #pragma unroll
    for (int i = 0; i < 4; ++i)
        #pragma unroll
        for (int j = 0; j < 4; ++j) acc[i][j] = f32x4{0.f,0.f,0.f,0.f};

    // prologue: stage k0=0 into buffer 0
    gload16(xb + (size_t)(m0+row0)*EMB + c0*8, (char*)As[0] + dst0*16);
    gload16(W  + (size_t)(n0+row0)*EMB + c0*8, (char*)Bs[0] + dst0*16);
    gload16(xb + (size_t)(m0+row1)*EMB + c1*8, (char*)As[0] + dst1*16);
    gload16(W  + (size_t)(n0+row1)*EMB + c1*8, (char*)Bs[0] + dst1*16);
    __syncthreads();

    for (int kk = 0; kk < EMB/32; ++kk) {
        const int cur = kk & 1;
        if (kk < EMB/32 - 1) {              // stage next tile into other buffer
            int k0 = (kk+1) * 32;
            gload16(xb + (size_t)(m0+row0)*EMB + k0 + c0*8, (char*)As[cur^1] + dst0*16);
            gload16(W  + (size_t)(n0+row0)*EMB + k0 + c0*8, (char*)Bs[cur^1] + dst0*16);
            gload16(xb + (size_t)(m0+row1)*EMB + k0 + c1*8, (char*)As[cur^1] + dst1*16);
            gload16(W  + (size_t)(n0+row1)*EMB + k0 + c1*8, (char*)Bs[cur^1] + dst1*16);
        }
        bf16x8 af[4], bf[4];
        #pragma unroll
        for (int i = 0; i < 4; ++i) {
            int ar = 64*wr + 16*i + (lane & 15);
            int ac = (lane >> 4) ^ ((ar >> 1) & 3);
            af[i] = *(const bf16x8*)((const char*)As[cur] + ar*64 + ac*16);
            int br = 64*wc + 16*i + (lane & 15);
            int bc = (lane >> 4) ^ ((br >> 1) & 3);
            bf[i] = *(const bf16x8*)((const char*)Bs[cur] + br*64 + bc*16);
        }
        #pragma unroll
        for (int i = 0; i < 4; ++i)
            #pragma unroll
            for (int j = 0; j < 4; ++j)
                acc[i][j] = __builtin_amdgcn_mfma_f32_16x16x32_bf16(af[i], bf[j], acc[i][j], 0, 0, 0);
        __syncthreads();                    // next buffer staged + readers done
    }

    #pragma unroll
    for (int j = 0; j < 4; ++j) {
        int col = n0 + 64*wc + 16*j + (lane & 15);
        float bvv = bias[col];
        #pragma unroll
        for (int i = 0; i < 4; ++i) {
            int rw0 = m0 + 64*wr + 16*i + (lane >> 4) * 4;
            #pragma unroll
            for (int r = 0; r < 4; ++r)
                out[(size_t)(rw0+r)*EMB + col] = f2bf((acc[i][j][r] + bvv) * scale);
        }
    }
}

// Final projection: C bf16 @ Wt_o + bo -> fp32 out. BM=64 x BN=128, dbuf.
__global__ __launch_bounds__(256)
void gemm_out(const unsigned short* __restrict__ Cb, const unsigned short* __restrict__ Wto,
              const float* __restrict__ bo, float* __restrict__ out) {
    __shared__ __align__(16) unsigned short As[2][64*32];
    __shared__ __align__(16) unsigned short Bs[2][128*32];

    const int tid = threadIdx.x, lane = tid & 63, wid = tid >> 6;
    const int m0 = blockIdx.y * 64, n0 = blockIdx.x * 128;
    const int wr = wid >> 1, wc = wid & 1;     // 2(m) x 2(n) waves, 32x64 each

    const int arow_ = tid >> 2, ac_ = (tid & 3) ^ ((arow_ >> 1) & 3);
    const int ci1 = 256 + tid;
    const int brow0 = tid >> 2, bc0 = (tid & 3) ^ ((brow0 >> 1) & 3);
    const int brow1 = ci1 >> 2, bc1 = (ci1 & 3) ^ ((brow1 >> 1) & 3);
    const int dst0 = wid*64, dst1 = 256 + wid*64;

    f32x4 acc[2][4];
    #pragma unroll
    for (int i = 0; i < 2; ++i)
        #pragma unroll
        for (int j = 0; j < 4; ++j) acc[i][j] = f32x4{0.f,0.f,0.f,0.f};

    gload16(Cb  + (size_t)(m0+arow_)*EMB + ac_*8, (char*)As[0] + dst0*16);
    gload16(Wto + (size_t)(n0+brow0)*EMB + bc0*8, (char*)Bs[0] + dst0*16);
    gload16(Wto + (size_t)(n0+brow1)*EMB + bc1*8, (char*)Bs[0] + dst1*16);
    __syncthreads();

    for (int kk = 0; kk < EMB/32; ++kk) {
        const int cur = kk & 1;
        if (kk < EMB/32 - 1) {
            int k0 = (kk+1) * 32;
            gload16(Cb  + (size_t)(m0+arow_)*EMB + k0 + ac_*8, (char*)As[cur^1] + dst0*16);
            gload16(Wto + (size_t)(n0+brow0)*EMB + k0 + bc0*8, (char*)Bs[cur^1] + dst0*16);
            gload16(Wto + (size_t)(n0+brow1)*EMB + k0 + bc1*8, (char*)Bs[cur^1] + dst1*16);
        }
        bf16x8 af[2], bf[4];
        #pragma unroll
        for (int i = 0; i < 2; ++i) {
            int ar = 32*wr + 16*i + (lane & 15);
            int ac = (lane >> 4) ^ ((ar >> 1) & 3);
            af[i] = *(const bf16x8*)((const char*)As[cur] + ar*64 + ac*16);
        }
        #pragma unroll
        for (int j = 0; j < 4; ++j) {
            int br = 64*wc + 16*j + (lane & 15);
            int bc = (lane >> 4) ^ ((br >> 1) & 3);
            bf[j] = *(const bf16x8*)((const char*)Bs[cur] + br*64 + bc*16);
        }
        #pragma unroll
        for (int i = 0; i < 2; ++i)
            #pragma unroll
            for (int j = 0; j < 4; ++j)
                acc[i][j] = __builtin_amdgcn_mfma_f32_16x16x32_bf16(af[i], bf[j], acc[i][j], 0, 0, 0);
        __syncthreads();
    }

    #pragma unroll
    for (int j = 0; j < 4; ++j) {
        int col = n0 + 64*wc + 16*j + (lane & 15);
        float bvv = bo[col];
        #pragma unroll
        for (int i = 0; i < 2; ++i) {
            int row0 = m0 + 32*wr + 16*i + (lane >> 4) * 4;
            #pragma unroll
            for (int r = 0; r < 4; ++r)
                out[(size_t)(row0+r)*EMB + col] = acc[i][j][r] + bvv;
        }
    }
}

// ---------------------------------------------------------------------------
// MFMA flash attention v5: QBLK=128 (4 waves x 32 q-rows), swapped QK^T,
// no-max softmax (scores in log2 units), double-buffered K/V^T via
// global_load_lds, 1 barrier/tile. K/V fragments reused across both q-halves.
__global__ __launch_bounds__(256, 2)
void attn(const unsigned short* __restrict__ Qg, const unsigned short* __restrict__ Kg,
          const unsigned short* __restrict__ Vt, unsigned short* __restrict__ Cg) {
    __shared__ __align__(16) unsigned short Ks[2][64*64];
    __shared__ __align__(16) unsigned short Vs[2][64*64];

    const int tid = threadIdx.x, lane = tid & 63, wid = tid >> 6;
    const int qb = blockIdx.x, bh = blockIdx.y;
    const int b = bh >> 4, h = bh & 15;
    const size_t base = (size_t)b * SEQ * EMB + (size_t)h * HDIM;
    const unsigned short* Qp = Qg + base + (size_t)qb * 128 * EMB;
    const unsigned short* Kp = Kg + base;
    const unsigned short* Vtp = Vt + (size_t)bh * HDIM * SEQ;   // [d][S]

    // ---- prologue: stage 128-row Q tile through Ks[0..1] (16 KB) ----
    #pragma unroll
    for (int it = 0; it < 4; ++it) {
        int ci = it*256 + tid, row = ci >> 3, c = (ci & 7) ^ (row & 7);
        gload16(Qp + (size_t)row*EMB + c*8, (char*)Ks[0] + (it*256 + wid*64)*16);
    }
    __syncthreads();
    bf16x8 qf[2][2];                        // [q-half][kc]
    #pragma unroll
    for (int qh = 0; qh < 2; ++qh)
        #pragma unroll
        for (int kc = 0; kc < 2; ++kc) {
            int r = 32*wid + 16*qh + (lane & 15);
            int c = ((lane >> 4) + 4*kc) ^ (r & 7);
            qf[qh][kc] = *(const bf16x8*)((const char*)Ks[0] + r*128 + c*16);
        }
    __syncthreads();                        // all waves read Q before overwrite

    // stage tile 0: K -> Ks[0], V^T -> Vs[0]
    #pragma unroll
    for (int it = 0; it < 2; ++it) {
        int ci = it*256 + tid, row = ci >> 3, c = (ci & 7) ^ (row & 7);
        gload16(Kp + (size_t)row*EMB + c*8, (char*)Ks[0] + (it*256 + wid*64)*16);
        gload16(Vtp + (size_t)row*SEQ + c*8, (char*)Vs[0] + (it*256 + wid*64)*16);
    }
    __syncthreads();

    f32x4 O[2][4];                          // [q-half][d-frag]
    #pragma unroll
    for (int qh = 0; qh < 2; ++qh)
        #pragma unroll
        for (int j = 0; j < 4; ++j) O[qh][j] = f32x4{0.f,0.f,0.f,0.f};
    float l_run[2] = {0.f, 0.f};

    for (int kt = 0; kt < SEQ/64; ++kt) {
        const int cur = kt & 1, nxt = cur ^ 1;
        if (kt < SEQ/64 - 1) {              // issue next-tile loads early
            const unsigned short* Kt = Kp + (size_t)(kt+1)*64*EMB;
            const unsigned short* Vn = Vtp + (size_t)(kt+1)*64;
            #pragma unroll
            for (int it = 0; it < 2; ++it) {
                int ci = it*256 + tid, row = ci >> 3, c = (ci & 7) ^ (row & 7);
                gload16(Kt + (size_t)row*EMB + c*8, (char*)Ks[nxt] + (it*256 + wid*64)*16);
                gload16(Vn + (size_t)row*SEQ + c*8, (char*)Vs[nxt] + (it*256 + wid*64)*16);
            }
        }

        // ---- swapped QK^T: S^T, lane holds 16 scores per q-half ----
        f32x4 s[4][2];                      // [key-frag][q-half]
        __builtin_amdgcn_s_setprio(1);
        #pragma unroll
        for (int nk = 0; nk < 4; ++nk) {
            #pragma unroll
            for (int qh = 0; qh < 2; ++qh) s[nk][qh] = f32x4{0.f,0.f,0.f,0.f};
            #pragma unroll
            for (int kc = 0; kc < 2; ++kc) {
                int r = 16*nk + (lane & 15);
                int c = ((lane >> 4) + 4*kc) ^ (r & 7);
                bf16x8 kf = *(const bf16x8*)((const char*)Ks[cur] + r*128 + c*16);
                #pragma unroll
                for (int qh = 0; qh < 2; ++qh)
                    s[nk][qh] = __builtin_amdgcn_mfma_f32_16x16x32_bf16(kf, qf[qh][kc], s[nk][qh], 0, 0, 0);
            }
        }
        __builtin_amdgcn_s_setprio(0);

        // ---- softmax without max-shift: p = 2^s ----
        bf16x8 pf[2][2];                    // [q-half][kc]
        #pragma unroll
        for (int qh = 0; qh < 2; ++qh) {
            float psv[4];
            #pragma unroll
            for (int nk = 0; nk < 4; ++nk) {
                #pragma unroll
                for (int r = 0; r < 4; ++r)
                    s[nk][qh][r] = exp2f(s[nk][qh][r]);
                psv[nk] = (s[nk][qh][0] + s[nk][qh][1]) + (s[nk][qh][2] + s[nk][qh][3]);
            }
            float ps = (psv[0] + psv[1]) + (psv[2] + psv[3]);
            ps += __shfl_xor(ps, 16);
            ps += __shfl_xor(ps, 32);
            l_run[qh] += ps;

            // pack P -> bf16 pairs, exchange to PV A-fragment layout
            unsigned pk[4][2];
            #pragma unroll
            for (int nk = 0; nk < 4; ++nk) {
                pk[nk][0] = cvt_pk_bf16(s[nk][qh][0], s[nk][qh][1]);
                pk[nk][1] = cvt_pk_bf16(s[nk][qh][2], s[nk][qh][3]);
            }
            const int hh = lane >> 4;
            const int srcA = (((hh << 1) & 3) << 4) | (lane & 15);
            const int srcB = srcA + 16;
            const int hs = hh >> 1;
            #pragma unroll
            for (int kc = 0; kc < 2; ++kc) {
                union { unsigned u[4]; bf16x8 v; } cvt;
                unsigned a0 = __shfl((int)pk[2*kc][0], srcA), b0 = __shfl((int)pk[2*kc+1][0], srcA);
                cvt.u[0] = hs ? b0 : a0;
                unsigned a1 = __shfl((int)pk[2*kc][1], srcA), b1 = __shfl((int)pk[2*kc+1][1], srcA);
                cvt.u[1] = hs ? b1 : a1;
                unsigned a2 = __shfl((int)pk[2*kc][0], srcB), b2 = __shfl((int)pk[2*kc+1][0], srcB);
                cvt.u[2] = hs ? b2 : a2;
                unsigned a3 = __shfl((int)pk[2*kc][1], srcB), b3 = __shfl((int)pk[2*kc+1][1], srcB);
                cvt.u[3] = hs ? b3 : a3;
                pf[qh][kc] = cvt.v;
            }
        }

        // ---- PV: V^T fragments shared across both q-halves ----
        __builtin_amdgcn_s_setprio(1);
        #pragma unroll
        for (int jd = 0; jd < 4; ++jd) {
            #pragma unroll
            for (int kc = 0; kc < 2; ++kc) {
                int d = 16*jd + (lane & 15);
                int c = ((lane >> 4) + 4*kc) ^ (d & 7);
                bf16x8 vf = *(const bf16x8*)((const char*)Vs[cur] + d*128 + c*16);
                #pragma unroll
                for (int qh = 0; qh < 2; ++qh)
                    O[qh][jd] = __builtin_amdgcn_mfma_f32_16x16x32_bf16(pf[qh][kc], vf, O[qh][jd], 0, 0, 0);
            }
        }
        __builtin_amdgcn_s_setprio(0);
        __syncthreads();
    }

    // ---- epilogue ----
    unsigned short* Cp = Cg + base + (size_t)qb * 128 * EMB;
    #pragma unroll
    for (int qh = 0; qh < 2; ++qh) {
        float inv[4];
        #pragma unroll
        for (int r = 0; r < 4; ++r) inv[r] = 1.f / __shfl(l_run[qh], (lane >> 4)*4 + r);
        #pragma unroll
        for (int jd = 0; jd < 4; ++jd)
            #pragma unroll
            for (int r = 0; r < 4; ++r) {
                int row = 32*wid + 16*qh + (lane >> 4)*4 + r;
                int col = 16*jd + (lane & 15);
                Cp[(size_t)row*EMB + col] = f2bf(O[qh][jd][r] * inv[r]);
            }
    }
}

// ---------------------------------------------------------------------------
extern "C" void kernel_launch(void* const* d_in, const int* in_sizes, int n_in,
                              void* d_out, int out_size, void* d_ws, size_t ws_size,
                              hipStream_t stream) {
    const float* x  = (const float*)d_in[0];
    const float* Wq = (const float*)d_in[1];
    const float* bq = (const float*)d_in[2];
    const float* Wk = (const float*)d_in[3];
    const float* bk = (const float*)d_in[4];
    const float* Wv = (const float*)d_in[5];
    const float* bv = (const float*)d_in[6];
    const float* Wo = (const float*)d_in[7];
    const float* bo = (const float*)d_in[8];
    float* out = (float*)d_out;

    unsigned short* xb = (unsigned short*)d_ws;                 // 8 MB
    unsigned short* Wt = xb + (size_t)NTOK * EMB;               // 8 MB (4 mats)
    unsigned short* Qb = Wt + (size_t)4 * EMB * EMB;            // 8 MB
    unsigned short* Kb = Qb + (size_t)NTOK * EMB;               // 8 MB
    unsigned short* Vb = Kb + (size_t)NTOK * EMB;               // 8 MB
    unsigned short* Cb = Vb + (size_t)NTOK * EMB;               // 8 MB
    unsigned short* Vtr = Cb + (size_t)NTOK * EMB;              // 8 MB

    conv_x<<<dim3((NTOK*EMB)/(256*8)), 256, 0, stream>>>(x, xb);
    conv_wt<<<dim3(16, 16, 4), 256, 0, stream>>>(Wq, Wk, Wv, Wo, Wt);
    gemm_qkv<<<dim3(8, 32, 3), 256, 0, stream>>>(xb, Wt, bq, bk, bv, Qb, Kb, Vb);
    transpose_v<<<dim3(SEQ/64, BATCH*NHEAD), 256, 0, stream>>>(Vb, Vtr);
    attn<<<dim3(SEQ/128, BATCH*NHEAD), 256, 0, stream>>>(Qb, Kb, Vtr, Cb);
    gemm_out<<<dim3(EMB/128, NTOK/64), 256, 0, stream>>>(Cb, Wt + (size_t)3*EMB*EMB, bo, out);
}

// Round 8
// 225.322 us; speedup vs baseline: 1.0079x; 1.0079x over previous
//
#include <hip/hip_runtime.h>
#include <cstdint>

#define BATCH 2
#define SEQ   2048
#define EMB   1024
#define NHEAD 16
#define HDIM  64
#define NTOK  (BATCH*SEQ)

typedef __attribute__((ext_vector_type(8))) short bf16x8;
typedef __attribute__((ext_vector_type(8))) short short8;
typedef __attribute__((ext_vector_type(4))) float f32x4;

__device__ inline unsigned short f2bf(float f) {
    unsigned u = __float_as_uint(f);
    u += 0x7FFF + ((u >> 16) & 1);          // RNE
    return (unsigned short)(u >> 16);
}

__device__ inline unsigned cvt_pk_bf16(float lo, float hi) {
    unsigned r;
    asm("v_cvt_pk_bf16_f32 %0, %1, %2" : "=v"(r) : "v"(lo), "v"(hi));
    return r;
}

__device__ inline void gload16(const void* g, void* lds) {
    __builtin_amdgcn_global_load_lds(
        (const __attribute__((address_space(1))) unsigned int*)g,
        (__attribute__((address_space(3))) unsigned int*)lds, 16, 0, 0);
}

// ---------------------------------------------------------------------------
// x fp32 -> bf16
__global__ __launch_bounds__(256)
void conv_x(const float* __restrict__ x, unsigned short* __restrict__ xb) {
    int i = (blockIdx.x * 256 + threadIdx.x) * 8;
    float4 a = *(const float4*)(x + i);
    float4 b = *(const float4*)(x + i + 4);
    short8 o;
    o[0]=f2bf(a.x); o[1]=f2bf(a.y); o[2]=f2bf(a.z); o[3]=f2bf(a.w);
    o[4]=f2bf(b.x); o[5]=f2bf(b.y); o[6]=f2bf(b.z); o[7]=f2bf(b.w);
    *(short8*)(xb + i) = o;
}

// W[k][n] fp32 -> Wt[n][k] bf16 (4 matrices, z-indexed), 64x64 tiles via LDS
__global__ __launch_bounds__(256)
void conv_wt(const float* __restrict__ Wq, const float* __restrict__ Wk,
             const float* __restrict__ Wv, const float* __restrict__ Wo,
             unsigned short* __restrict__ Wt) {
    const float* W = blockIdx.z==0?Wq : blockIdx.z==1?Wk : blockIdx.z==2?Wv : Wo;
    unsigned short* out = Wt + (size_t)blockIdx.z * EMB * EMB;
    __shared__ float T[64][68];
    const int t = threadIdx.x;
    const int k0 = blockIdx.x * 64, n0 = blockIdx.y * 64;
    #pragma unroll
    for (int rr = 0; rr < 4; ++rr) {
        int row = (t >> 4) + 16 * rr;
        float4 v = *(const float4*)(W + (size_t)(k0+row)*EMB + n0 + (t&15)*4);
        *(float4*)&T[row][(t&15)*4] = v;
    }
    __syncthreads();
    #pragma unroll
    for (int it = 0; it < 2; ++it) {
        int ci = it*256 + t;
        int nr = ci >> 3, kc = ci & 7;
        short8 o;
        #pragma unroll
        for (int j = 0; j < 8; ++j) o[j] = f2bf(T[kc*8+j][nr]);
        *(short8*)(out + (size_t)(n0+nr)*EMB + k0 + kc*8) = o;
    }
}

// V [B,S,H*D] bf16 -> Vt [B*H, D, S] bf16. 64x64 tiles, LDS stride 65.
__global__ __launch_bounds__(256)
void transpose_v(const unsigned short* __restrict__ Vb, unsigned short* __restrict__ Vt) {
    __shared__ unsigned short T[64*65];
    const int t = threadIdx.x;
    const int s0 = blockIdx.x * 64;
    const int bh = blockIdx.y;
    const int b = bh >> 4, h = bh & 15;
    const unsigned short* src = Vb + ((size_t)b*SEQ + s0)*EMB + h*HDIM;
    #pragma unroll
    for (int it = 0; it < 2; ++it) {
        int ci = it*256 + t;
        int r = ci >> 3, c = ci & 7;            // r = s-row, c = d-chunk
        short8 v = *(const short8*)(src + (size_t)r*EMB + c*8);
        #pragma unroll
        for (int j = 0; j < 8; ++j) T[r*65 + c*8 + j] = (unsigned short)v[j];
    }
    __syncthreads();
    unsigned short* dst = Vt + (size_t)bh * HDIM * SEQ + s0;
    #pragma unroll
    for (int it = 0; it < 2; ++it) {
        int ci = it*256 + t;
        int d = ci >> 3, c = ci & 7;            // d = out row, c = s-chunk
        short8 o;
        #pragma unroll
        for (int j = 0; j < 8; ++j) o[j] = (short)T[(c*8 + j)*65 + d];
        *(short8*)(dst + (size_t)d*SEQ + c*8) = o;
    }
}

// ---------------------------------------------------------------------------
// Fused QKV GEMM: [4096,1024] @ Wt[3072][1024]^T -> Q/K/V bf16.
// BM=256, BN=256, BK=64, 8 waves (wave tile 128x64), double-buffered 2-phase,
// 128 KB LDS. Staging swizzle: 64-elem rows, 16B chunk c at slot c^(row&7),
// pre-swizzled on the GLOBAL source (linear LDS dest), same XOR on read.
// Q output scaled by 0.125*log2(e) (attn scores in log2 units).
__global__ __launch_bounds__(512, 2)
void gemm_qkv(const unsigned short* __restrict__ xb, const unsigned short* __restrict__ Wt,
              const float* __restrict__ bq, const float* __restrict__ bk,
              const float* __restrict__ bv,
              unsigned short* __restrict__ Qb, unsigned short* __restrict__ Kb,
              unsigned short* __restrict__ Vb) {
    __shared__ __align__(16) unsigned short As[2][256*64];
    __shared__ __align__(16) unsigned short Bs[2][256*64];

    const int tid = threadIdx.x, lane = tid & 63, wid = tid >> 6;
    const int m0 = blockIdx.y * 256, n0 = blockIdx.x * 256;
    const int wr = wid >> 2, wc = wid & 3;     // 2(m) x 4(n) waves, 128x64 each

    f32x4 acc[8][4];
    #pragma unroll
    for (int i = 0; i < 8; ++i)
        #pragma unroll
        for (int j = 0; j < 4; ++j) acc[i][j] = f32x4{0.f,0.f,0.f,0.f};

    // per-thread staging chunks (4 per matrix per K-step)
    int srow[4], sc[4], sdst[4];
    #pragma unroll
    for (int it = 0; it < 4; ++it) {
        int ci = it*512 + tid;
        srow[it] = ci >> 3;
        sc[it]   = (ci & 7) ^ (srow[it] & 7);
        sdst[it] = (it*512 + wid*64) * 16;      // wave-uniform LDS base
    }

    // prologue: stage k0=0 into buffer 0
    #pragma unroll
    for (int it = 0; it < 4; ++it) {
        gload16(xb + (size_t)(m0+srow[it])*EMB + sc[it]*8, (char*)As[0] + sdst[it]);
        gload16(Wt + (size_t)(n0+srow[it])*EMB + sc[it]*8, (char*)Bs[0] + sdst[it]);
    }
    __syncthreads();

    for (int kk = 0; kk < EMB/64; ++kk) {
        const int cur = kk & 1;
        if (kk < EMB/64 - 1) {                  // stage next K-tile early
            int k0 = (kk+1) * 64;
            #pragma unroll
            for (int it = 0; it < 4; ++it) {
                gload16(xb + (size_t)(m0+srow[it])*EMB + k0 + sc[it]*8, (char*)As[cur^1] + sdst[it]);
                gload16(Wt + (size_t)(n0+srow[it])*EMB + k0 + sc[it]*8, (char*)Bs[cur^1] + sdst[it]);
            }
        }
        #pragma unroll
        for (int kc = 0; kc < 2; ++kc) {
            bf16x8 af[8], bf[4];
            #pragma unroll
            for (int i = 0; i < 8; ++i) {
                int r = 128*wr + 16*i + (lane & 15);
                int c = ((lane >> 4) + 4*kc) ^ (r & 7);
                af[i] = *(const bf16x8*)((const char*)As[cur] + r*128 + c*16);
            }
            #pragma unroll
            for (int j = 0; j < 4; ++j) {
                int r = 64*wc + 16*j + (lane & 15);
                int c = ((lane >> 4) + 4*kc) ^ (r & 7);
                bf[j] = *(const bf16x8*)((const char*)Bs[cur] + r*128 + c*16);
            }
            #pragma unroll
            for (int i = 0; i < 8; ++i)
                #pragma unroll
                for (int j = 0; j < 4; ++j)
                    acc[i][j] = __builtin_amdgcn_mfma_f32_16x16x32_bf16(af[i], bf[j], acc[i][j], 0, 0, 0);
        }
        __syncthreads();
    }

    // epilogue: n0 selects z (BN=256 divides 1024, no straddle)
    const int zsel = n0 >> 10;
    const float* bias = zsel==0 ? bq : zsel==1 ? bk : bv;
    unsigned short* out = zsel==0 ? Qb : zsel==1 ? Kb : Vb;
    const int nL = n0 & 1023;
    const float scale = zsel==0 ? (0.125f * 1.44269504f) : 1.0f;

    #pragma unroll
    for (int j = 0; j < 4; ++j) {
        int colL = nL + 64*wc + 16*j + (lane & 15);
        float bvv = bias[colL];
        #pragma unroll
        for (int i = 0; i < 8; ++i) {
            int row0 = m0 + 128*wr + 16*i + (lane >> 4) * 4;
            #pragma unroll
            for (int r = 0; r < 4; ++r)
                out[(size_t)(row0+r)*EMB + colL] = f2bf((acc[i][j][r] + bvv) * scale);
        }
    }
}

// Final projection: C bf16 @ Wt_o + bo -> fp32 out. BM=64 x BN=128, dbuf.
__global__ __launch_bounds__(256)
void gemm_out(const unsigned short* __restrict__ Cb, const unsigned short* __restrict__ Wto,
              const float* __restrict__ bo, float* __restrict__ out) {
    __shared__ __align__(16) unsigned short As[2][64*32];
    __shared__ __align__(16) unsigned short Bs[2][128*32];

    const int tid = threadIdx.x, lane = tid & 63, wid = tid >> 6;
    const int m0 = blockIdx.y * 64, n0 = blockIdx.x * 128;
    const int wr = wid >> 1, wc = wid & 1;     // 2(m) x 2(n) waves, 32x64 each

    const int arow_ = tid >> 2, ac_ = (tid & 3) ^ ((arow_ >> 1) & 3);
    const int ci1 = 256 + tid;
    const int brow0 = tid >> 2, bc0 = (tid & 3) ^ ((brow0 >> 1) & 3);
    const int brow1 = ci1 >> 2, bc1 = (ci1 & 3) ^ ((brow1 >> 1) & 3);
    const int dst0 = wid*64, dst1 = 256 + wid*64;

    f32x4 acc[2][4];
    #pragma unroll
    for (int i = 0; i < 2; ++i)
        #pragma unroll
        for (int j = 0; j < 4; ++j) acc[i][j] = f32x4{0.f,0.f,0.f,0.f};

    gload16(Cb  + (size_t)(m0+arow_)*EMB + ac_*8, (char*)As[0] + dst0*16);
    gload16(Wto + (size_t)(n0+brow0)*EMB + bc0*8, (char*)Bs[0] + dst0*16);
    gload16(Wto + (size_t)(n0+brow1)*EMB + bc1*8, (char*)Bs[0] + dst1*16);
    __syncthreads();

    for (int kk = 0; kk < EMB/32; ++kk) {
        const int cur = kk & 1;
        if (kk < EMB/32 - 1) {
            int k0 = (kk+1) * 32;
            gload16(Cb  + (size_t)(m0+arow_)*EMB + k0 + ac_*8, (char*)As[cur^1] + dst0*16);
            gload16(Wto + (size_t)(n0+brow0)*EMB + k0 + bc0*8, (char*)Bs[cur^1] + dst0*16);
            gload16(Wto + (size_t)(n0+brow1)*EMB + k0 + bc1*8, (char*)Bs[cur^1] + dst1*16);
        }
        bf16x8 af[2], bf[4];
        #pragma unroll
        for (int i = 0; i < 2; ++i) {
            int ar = 32*wr + 16*i + (lane & 15);
            int ac = (lane >> 4) ^ ((ar >> 1) & 3);
            af[i] = *(const bf16x8*)((const char*)As[cur] + ar*64 + ac*16);
        }
        #pragma unroll
        for (int j = 0; j < 4; ++j) {
            int br = 64*wc + 16*j + (lane & 15);
            int bc = (lane >> 4) ^ ((br >> 1) & 3);
            bf[j] = *(const bf16x8*)((const char*)Bs[cur] + br*64 + bc*16);
        }
        #pragma unroll
        for (int i = 0; i < 2; ++i)
            #pragma unroll
            for (int j = 0; j < 4; ++j)
                acc[i][j] = __builtin_amdgcn_mfma_f32_16x16x32_bf16(af[i], bf[j], acc[i][j], 0, 0, 0);
        __syncthreads();
    }

    #pragma unroll
    for (int j = 0; j < 4; ++j) {
        int col = n0 + 64*wc + 16*j + (lane & 15);
        float bvv = bo[col];
        #pragma unroll
        for (int i = 0; i < 2; ++i) {
            int row0 = m0 + 32*wr + 16*i + (lane >> 4) * 4;
            #pragma unroll
            for (int r = 0; r < 4; ++r)
                out[(size_t)(row0+r)*EMB + col] = acc[i][j][r] + bvv;
        }
    }
}

// ---------------------------------------------------------------------------
// MFMA flash attention (R6 config): QBLK=64, swapped QK^T, no-max softmax
// (scores in log2 units), double-buffered K/V^T via global_load_lds,
// 1 barrier/tile. 4 waves; wave w owns q rows 16w..16w+15.
__global__ __launch_bounds__(256, 4)
void attn(const unsigned short* __restrict__ Qg, const unsigned short* __restrict__ Kg,
          const unsigned short* __restrict__ Vt, unsigned short* __restrict__ Cg) {
    __shared__ __align__(16) unsigned short Ks[2][64*64];
    __shared__ __align__(16) unsigned short Vs[2][64*64];

    const int tid = threadIdx.x, lane = tid & 63, wid = tid >> 6;
    const int qb = blockIdx.x, bh = blockIdx.y;
    const int b = bh >> 4, h = bh & 15;
    const size_t base = (size_t)b * SEQ * EMB + (size_t)h * HDIM;
    const unsigned short* Qp = Qg + base + (size_t)qb * 64 * EMB;
    const unsigned short* Kp = Kg + base;
    const unsigned short* Vtp = Vt + (size_t)bh * HDIM * SEQ;   // [d][S]

    // ---- prologue: stage Q into Ks[0], hoist Q fragments to registers ----
    #pragma unroll
    for (int it = 0; it < 2; ++it) {
        int ci = it*256 + tid, row = ci >> 3, c = (ci & 7) ^ (row & 7);
        gload16(Qp + (size_t)row*EMB + c*8, (char*)Ks[0] + (it*256 + wid*64)*16);
    }
    __syncthreads();
    bf16x8 qf[2];
    #pragma unroll
    for (int kc = 0; kc < 2; ++kc) {
        int r = 16*wid + (lane & 15);
        int c = ((lane >> 4) + 4*kc) ^ (r & 7);
        qf[kc] = *(const bf16x8*)((const char*)Ks[0] + r*128 + c*16);
    }
    __syncthreads();                        // all waves read Q before K0 overwrite

    // stage tile 0: K -> Ks[0], V^T -> Vs[0]
    #pragma unroll
    for (int it = 0; it < 2; ++it) {
        int ci = it*256 + tid, row = ci >> 3, c = (ci & 7) ^ (row & 7);
        gload16(Kp + (size_t)row*EMB + c*8, (char*)Ks[0] + (it*256 + wid*64)*16);
        gload16(Vtp + (size_t)row*SEQ + c*8, (char*)Vs[0] + (it*256 + wid*64)*16);
    }
    __syncthreads();

    f32x4 O[4];
    #pragma unroll
    for (int j = 0; j < 4; ++j) O[j] = f32x4{0.f,0.f,0.f,0.f};
    float l_run = 0.f;

    for (int kt = 0; kt < SEQ/64; ++kt) {
        const int cur = kt & 1, nxt = cur ^ 1;
        if (kt < SEQ/64 - 1) {              // issue next-tile loads early
            const unsigned short* Kt = Kp + (size_t)(kt+1)*64*EMB;
            const unsigned short* Vn = Vtp + (size_t)(kt+1)*64;
            #pragma unroll
            for (int it = 0; it < 2; ++it) {
                int ci = it*256 + tid, row = ci >> 3, c = (ci & 7) ^ (row & 7);
                gload16(Kt + (size_t)row*EMB + c*8, (char*)Ks[nxt] + (it*256 + wid*64)*16);
                gload16(Vn + (size_t)row*SEQ + c*8, (char*)Vs[nxt] + (it*256 + wid*64)*16);
            }
        }

        // ---- swapped QK^T: S^T tile, lane holds 16 scores for q=lane&15 ----
        f32x4 s[4];
        __builtin_amdgcn_s_setprio(1);
        #pragma unroll
        for (int nk = 0; nk < 4; ++nk) {
            s[nk] = f32x4{0.f,0.f,0.f,0.f};
            #pragma unroll
            for (int kc = 0; kc < 2; ++kc) {
                int r = 16*nk + (lane & 15);
                int c = ((lane >> 4) + 4*kc) ^ (r & 7);
                bf16x8 kf = *(const bf16x8*)((const char*)Ks[cur] + r*128 + c*16);
                s[nk] = __builtin_amdgcn_mfma_f32_16x16x32_bf16(kf, qf[kc], s[nk], 0, 0, 0);
            }
        }
        __builtin_amdgcn_s_setprio(0);

        // ---- softmax without max-shift: p = 2^s directly ----
        float psv[4];
        #pragma unroll
        for (int nk = 0; nk < 4; ++nk) {
            #pragma unroll
            for (int r = 0; r < 4; ++r)
                s[nk][r] = exp2f(s[nk][r]);
            psv[nk] = (s[nk][0] + s[nk][1]) + (s[nk][2] + s[nk][3]);
        }
        float ps = (psv[0] + psv[1]) + (psv[2] + psv[3]);
        ps += __shfl_xor(ps, 16);
        ps += __shfl_xor(ps, 32);
        l_run += ps;

        // ---- pack P -> bf16 pairs, exchange to PV A-fragment layout ----
        unsigned pk[4][2];
        #pragma unroll
        for (int nk = 0; nk < 4; ++nk) {
            pk[nk][0] = cvt_pk_bf16(s[nk][0], s[nk][1]);
            pk[nk][1] = cvt_pk_bf16(s[nk][2], s[nk][3]);
        }
        const int hh = lane >> 4;
        const int srcA = (((hh << 1) & 3) << 4) | (lane & 15);
        const int srcB = srcA + 16;
        const int hs = hh >> 1;
        bf16x8 pf[2];
        #pragma unroll
        for (int kc = 0; kc < 2; ++kc) {
            union { unsigned u[4]; bf16x8 v; } cvt;
            unsigned a0 = __shfl((int)pk[2*kc][0], srcA), b0 = __shfl((int)pk[2*kc+1][0], srcA);
            cvt.u[0] = hs ? b0 : a0;
            unsigned a1 = __shfl((int)pk[2*kc][1], srcA), b1 = __shfl((int)pk[2*kc+1][1], srcA);
            cvt.u[1] = hs ? b1 : a1;
            unsigned a2 = __shfl((int)pk[2*kc][0], srcB), b2 = __shfl((int)pk[2*kc+1][0], srcB);
            cvt.u[2] = hs ? b2 : a2;
            unsigned a3 = __shfl((int)pk[2*kc][1], srcB), b3 = __shfl((int)pk[2*kc+1][1], srcB);
            cvt.u[3] = hs ? b3 : a3;
            pf[kc] = cvt.v;
        }

        // ---- PV (V^T fragments straight from LDS, same pattern as K) ----
        __builtin_amdgcn_s_setprio(1);
        #pragma unroll
        for (int jd = 0; jd < 4; ++jd) {
            #pragma unroll
            for (int kc = 0; kc < 2; ++kc) {
                int d = 16*jd + (lane & 15);
                int c = ((lane >> 4) + 4*kc) ^ (d & 7);
                bf16x8 vf = *(const bf16x8*)((const char*)Vs[cur] + d*128 + c*16);
                O[jd] = __builtin_amdgcn_mfma_f32_16x16x32_bf16(pf[kc], vf, O[jd], 0, 0, 0);
            }
        }
        __builtin_amdgcn_s_setprio(0);
        __syncthreads();
    }

    // ---- epilogue ----
    float inv[4];
    #pragma unroll
    for (int r = 0; r < 4; ++r) inv[r] = 1.f / __shfl(l_run, (lane >> 4)*4 + r);
    unsigned short* Cp = Cg + base + (size_t)qb * 64 * EMB;
    #pragma unroll
    for (int jd = 0; jd < 4; ++jd)
        #pragma unroll
        for (int r = 0; r < 4; ++r) {
            int row = 16*wid + (lane >> 4)*4 + r;
            int col = 16*jd + (lane & 15);
            Cp[(size_t)row*EMB + col] = f2bf(O[jd][r] * inv[r]);
        }
}

// ---------------------------------------------------------------------------
extern "C" void kernel_launch(void* const* d_in, const int* in_sizes, int n_in,
                              void* d_out, int out_size, void* d_ws, size_t ws_size,
                              hipStream_t stream) {
    const float* x  = (const float*)d_in[0];
    const float* Wq = (const float*)d_in[1];
    const float* bq = (const float*)d_in[2];
    const float* Wk = (const float*)d_in[3];
    const float* bk = (const float*)d_in[4];
    const float* Wv = (const float*)d_in[5];
    const float* bv = (const float*)d_in[6];
    const float* Wo = (const float*)d_in[7];
    const float* bo = (const float*)d_in[8];
    float* out = (float*)d_out;

    unsigned short* xb = (unsigned short*)d_ws;                 // 8 MB
    unsigned short* Wt = xb + (size_t)NTOK * EMB;               // 8 MB (4 mats)
    unsigned short* Qb = Wt + (size_t)4 * EMB * EMB;            // 8 MB
    unsigned short* Kb = Qb + (size_t)NTOK * EMB;               // 8 MB
    unsigned short* Vb = Kb + (size_t)NTOK * EMB;               // 8 MB
    unsigned short* Cb = Vb + (size_t)NTOK * EMB;               // 8 MB
    unsigned short* Vtr = Cb + (size_t)NTOK * EMB;              // 8 MB

    conv_x<<<dim3((NTOK*EMB)/(256*8)), 256, 0, stream>>>(x, xb);
    conv_wt<<<dim3(16, 16, 4), 256, 0, stream>>>(Wq, Wk, Wv, Wo, Wt);
    gemm_qkv<<<dim3(12, 16), 512, 0, stream>>>(xb, Wt, bq, bk, bv, Qb, Kb, Vb);
    transpose_v<<<dim3(SEQ/64, BATCH*NHEAD), 256, 0, stream>>>(Vb, Vtr);
    attn<<<dim3(SEQ/64, BATCH*NHEAD), 256, 0, stream>>>(Qb, Kb, Vtr, Cb);
    gemm_out<<<dim3(EMB/128, NTOK/64), 256, 0, stream>>>(Cb, Wt + (size_t)3*EMB*EMB, bo, out);
}